// Round 7
// baseline (187.262 us; speedup 1.0000x reference)
//
#include <hip/hip_runtime.h>
#include <cstdint>
#include <cstddef>

// ---------------------------------------------------------------------------
// mask_moe: bit-exact vs harness reference (verified rounds 4/5/6, absmax 0.0).
// FROZEN arithmetic: partitionable threefry bits, f32 sequential-k FMA dots,
// f32 elementwise chain (softplus/normal/softmax), decision logic.
// Round 7: out_kernel 131072x128 -> 2048x256 (64 rows/block, LDS-staged g,
// streaming float4 stores). Gating + loss kernels unchanged.
// ---------------------------------------------------------------------------

namespace {

constexpr int kBH = 256;                  // B*H
constexpr int kL = 512;                   // L
constexpr int kE = 3;                     // experts
constexpr int kRows = kBH * kL;           // 131072 gating rows
constexpr int kXPad = 65;                 // LDS row stride (floats), bank-safe

__device__ __forceinline__ uint32_t rotl32(uint32_t v, int n) {
  return (v << n) | (v >> (32 - n));
}

// Threefry-2x32, 20 rounds, key = (0, 42)  [jax.random.key(42)]
__device__ __forceinline__ void threefry2x32_k42(uint32_t& x0, uint32_t& x1) {
  const uint32_t ks0 = 0u;
  const uint32_t ks1 = 42u;
  const uint32_t ks2 = 0u ^ 42u ^ 0x1BD11BDAu;
  x0 += ks0; x1 += ks1;
#define TF_ROUND(r) { x0 += x1; x1 = rotl32(x1, (r)); x1 ^= x0; }
  TF_ROUND(13) TF_ROUND(15) TF_ROUND(26) TF_ROUND(6)
  x0 += ks1; x1 += ks2 + 1u;
  TF_ROUND(17) TF_ROUND(29) TF_ROUND(16) TF_ROUND(24)
  x0 += ks2; x1 += ks0 + 2u;
  TF_ROUND(13) TF_ROUND(15) TF_ROUND(26) TF_ROUND(6)
  x0 += ks0; x1 += ks1 + 3u;
  TF_ROUND(17) TF_ROUND(29) TF_ROUND(16) TF_ROUND(24)
  x0 += ks1; x1 += ks2 + 4u;
  TF_ROUND(13) TF_ROUND(15) TF_ROUND(26) TF_ROUND(6)
  x0 += ks2; x1 += ks0 + 5u;
#undef TF_ROUND
}

// partitionable path: bits = x0 ^ x1 of threefry(key, (0, i))
__device__ __forceinline__ uint32_t jax_random_bits(uint32_t flat_idx) {
  uint32_t x0 = 0u;
  uint32_t x1 = flat_idx;
  threefry2x32_k42(x0, x1);
  return x0 ^ x1;
}

// jax.random.normal f32: uniform(-0.99999994, 1.0) then sqrt(2)*erfinv (XLA Giles poly)
__device__ float bits_to_normal(uint32_t bits) {
#pragma clang fp contract(off)
  const uint32_t fb = (bits >> 9) | 0x3F800000u;
  const float f = __uint_as_float(fb) - 1.0f;   // [0, 1)
  const float lo = -0.99999994f;                 // nextafterf(-1, 0)
  float u = f * 2.0f + lo;                       // (maxval-minval) == 2.0f exactly
  u = fmaxf(lo, u);
  float w = -log1pf(-(u * u));
  float p;
  if (w < 5.0f) {
    w = w - 2.5f;
    p = 2.81022636e-08f;
    p = 3.43273939e-07f + p * w;
    p = -3.5233877e-06f + p * w;
    p = -4.39150654e-06f + p * w;
    p = 0.00021858087f + p * w;
    p = -0.00125372503f + p * w;
    p = -0.00417768164f + p * w;
    p = 0.246640727f + p * w;
    p = 1.50140941f + p * w;
  } else {
    w = sqrtf(w) - 3.0f;
    p = -0.000200214257f;
    p = 0.000100950558f + p * w;
    p = 0.00134934322f + p * w;
    p = -0.00367342844f + p * w;
    p = 0.00573950773f + p * w;
    p = -0.0076224613f + p * w;
    p = 0.00943887047f + p * w;
    p = 1.00167406f + p * w;
    p = 2.83297682f + p * w;
  }
  const float einv = p * u;
  return 1.41421354f * einv;  // f32(sqrt(2)) * erfinv(u)
}

// jax.nn.softplus(x) = logaddexp(x, 0) = max(x,0) + log1p(exp(-|x|))
__device__ __forceinline__ float softplus_f32(float v) {
#pragma clang fp contract(off)
  const float amax = fmaxf(v, 0.0f);
  return amax + log1pf(expf(-fabsf(v)));
}

// ---------------------------------------------------------------------------
// Kernel 1: gating. One thread per row; x staged through LDS in 64-col tiles
// with coalesced cooperative loads (pad-65 layout -> <=2 lanes/bank, free).
// FROZEN: f32 sequential-k single-accumulator FMA order per expert.
// ---------------------------------------------------------------------------
__global__ __launch_bounds__(256) void gating_kernel(
    const float* __restrict__ x, const float* __restrict__ gw,
    const float* __restrict__ nw, float* __restrict__ g_out,
    float* __restrict__ kept_out, float* __restrict__ ent_out) {
  __shared__ float s_gw[kE * kL];
  __shared__ float s_nw[kE * kL];
  __shared__ float s_x[256 * kXPad];   // 66,560 B tile: 256 rows x 64 cols
  const int t = threadIdx.x;
  for (int i = t; i < kE * kL; i += 256) {
    s_gw[i] = gw[i];
    s_nw[i] = nw[i];
  }

  const int r0 = blockIdx.x * 256;
  const int r = r0 + t;  // this thread's row

  float accg[3] = {0.f, 0.f, 0.f};
  float accn[3] = {0.f, 0.f, 0.f};
  for (int c0 = 0; c0 < kL; c0 += 64) {
    __syncthreads();   // LDS tile reuse barrier (also covers weight staging)
    // cooperative coalesced load: 4096 float4s, 16 per thread
#pragma unroll
    for (int it = 0; it < 16; ++it) {
      const int fi = it * 256 + t;       // float4 index in tile
      const int row = fi >> 4;           // /16 float4s per row
      const int c4 = (fi & 15) << 2;     // col offset
      const float4 v =
          *reinterpret_cast<const float4*>(x + (size_t)(r0 + row) * kL + c0 + c4);
      float* dst = &s_x[row * kXPad + c4];
      dst[0] = v.x; dst[1] = v.y; dst[2] = v.z; dst[3] = v.w;
    }
    __syncthreads();
    {
#pragma clang fp contract(off)
      const float* xrow = &s_x[t * kXPad];
#pragma unroll 16
      for (int kk = 0; kk < 64; ++kk) {
        const float xq = xrow[kk];
        const int k = c0 + kk;
        accg[0] = fmaf(xq, s_gw[0 * kL + k], accg[0]);
        accg[1] = fmaf(xq, s_gw[1 * kL + k], accg[1]);
        accg[2] = fmaf(xq, s_gw[2 * kL + k], accg[2]);
        accn[0] = fmaf(xq, s_nw[0 * kL + k], accn[0]);
        accn[1] = fmaf(xq, s_nw[1 * kL + k], accn[1]);
        accn[2] = fmaf(xq, s_nw[2 * kL + k], accn[2]);
      }
    }
  }

  {
#pragma clang fp contract(off)
    float noisy[3];
    const uint32_t nbase = (uint32_t)r * 3u;
#pragma unroll
    for (int e = 0; e < 3; ++e) {
      const float cl = accg[e];
      const float sp = softplus_f32(accn[e]) + 0.01f;  // NOISE_EPS
      const float nz = bits_to_normal(jax_random_bits(nbase + (uint32_t)e));
      const float prod = nz * sp;        // separate rounding: mul then add
      noisy[e] = cl + prod;
    }
    // softmax over 3 experts (f32, max-subtracted)
    const float m = fmaxf(noisy[0], fmaxf(noisy[1], noisy[2]));
    float uu[3];
    uu[0] = expf(noisy[0] - m);
    uu[1] = expf(noisy[1] - m);
    uu[2] = expf(noisy[2] - m);
    const float ssum = (uu[0] + uu[1]) + uu[2];
    float p[3];
    p[0] = uu[0] / ssum;
    p[1] = uu[1] / ssum;
    p[2] = uu[2] / ssum;

    // stable descending argsort of 3
    int o0 = 0;
    if (p[1] > p[o0]) o0 = 1;
    if (p[2] > p[o0]) o0 = 2;
    const int i = (o0 == 0) ? 1 : 0;
    const int j = (o0 == 2) ? 1 : 2;
    const int o1 = (p[j] > p[i]) ? j : i;

    const float s0 = p[o0];
    const float s1 = p[o1];
    const bool keep2 = !(s0 > 0.5f);  // keep top-1 iff s0 > 0.5

    float g[3] = {0.f, 0.f, 0.f};
    g[o0] = 1.f;
    if (keep2) g[o1] = 1.f;

    float ent = 0.f;
    ent += p[0] * logf(p[0] + 1e-10f);
    ent += p[1] * logf(p[1] + 1e-10f);
    ent += p[2] * logf(p[2] + 1e-10f);

    const int bh = r >> 9;
    const int l = r & (kL - 1);
    g_out[r * 3 + 0] = g[0];
    g_out[r * 3 + 1] = g[1];
    g_out[r * 3 + 2] = g[2];
    // kept sorted probs, layout [jpos][l][bh] for coalesced reduction reads
    kept_out[(0 * kL + l) * kBH + bh] = s0;
    kept_out[(1 * kL + l) * kBH + bh] = keep2 ? s1 : 0.f;
    kept_out[(2 * kL + l) * kBH + bh] = 0.f;
    ent_out[r] = -ent;
  }
}

// ---------------------------------------------------------------------------
// Kernel 2a: parallel deterministic partials.
// 128 blocks x 256 threads (512 waves). Importance: wave wg reduces entries
// q = wg, wg+512, wg+1024 (coalesced 1KB float4 read + fixed f64 butterfly).
// Entropy: each block reduces a fixed 1024-row slice with a fixed LDS tree.
// ---------------------------------------------------------------------------
__global__ __launch_bounds__(256) void loss_partial_kernel(
    const float* __restrict__ kept, const float* __restrict__ ent,
    double* __restrict__ imp_ws, double* __restrict__ ent_ws) {
  __shared__ double red[256];
  const int t = threadIdx.x;
  const int ln = t & 63;
  const int wg = blockIdx.x * 4 + (t >> 6);   // global wave id, 0..511

  // importance entries
#pragma unroll
  for (int rep = 0; rep < 3; ++rep) {
    const int q = wg + rep * 512;
    const float4 v = reinterpret_cast<const float4*>(kept + (size_t)q * kBH)[ln];
    double s = ((double)v.x + (double)v.y) + ((double)v.z + (double)v.w);
#pragma unroll
    for (int off = 32; off > 0; off >>= 1) s += __shfl_xor(s, off, 64);
    if (ln == 0) imp_ws[q] = s;
  }

  // entropy partial: fixed slice of 1024 rows
  double a = 0.0;
#pragma unroll
  for (int it = 0; it < 4; ++it) {
    a += (double)ent[blockIdx.x * 1024 + it * 256 + t];
  }
  red[t] = a;
  __syncthreads();
  for (int off = 128; off > 0; off >>= 1) {
    if (t < off) red[t] += red[t + off];
    __syncthreads();
  }
  if (t == 0) ent_ws[blockIdx.x] = red[0];
}

// ---------------------------------------------------------------------------
// Kernel 2b: final loss combine (1 block, trivial).
// loss = var(importance, ddof=1)/(mean^2 + 1e-10) + 0.1 * ent_total/768
// ---------------------------------------------------------------------------
__global__ __launch_bounds__(256) void loss_final_kernel(
    const double* __restrict__ imp_ws, const double* __restrict__ ent_ws,
    float* __restrict__ loss_out) {
  __shared__ double red[256];
  __shared__ double s_mean;
  const int t = threadIdx.x;

  // mean of importance
  double a = 0.0;
  for (int i = t; i < kL * kE; i += 256) a += imp_ws[i];
  red[t] = a;
  __syncthreads();
  for (int off = 128; off > 0; off >>= 1) {
    if (t < off) red[t] += red[t + off];
    __syncthreads();
  }
  if (t == 0) s_mean = red[0] / (double)(kL * kE);
  __syncthreads();
  const double mean = s_mean;

  // variance (two-pass, ddof=1)
  double sq = 0.0;
  for (int i = t; i < kL * kE; i += 256) {
    const double d = imp_ws[i] - mean;
    sq += d * d;
  }
  red[t] = sq;
  __syncthreads();
  for (int off = 128; off > 0; off >>= 1) {
    if (t < off) red[t] += red[t + off];
    __syncthreads();
  }
  const double var_sum = red[0];
  __syncthreads();

  // entropy total
  double e = 0.0;
  for (int i = t; i < 128; i += 256) e += ent_ws[i];
  red[t] = e;
  __syncthreads();
  for (int off = 128; off > 0; off >>= 1) {
    if (t < off) red[t] += red[t + off];
    __syncthreads();
  }
  if (t == 0) {
    const double var = var_sum / (double)(kL * kE - 1);
    const double loss_imp = var / (mean * mean + 1e-10);
    const double loss_dyn = red[0] / 768.0;  // sum(axis=1).mean() over [BH,E]
    loss_out[0] = (float)(loss_imp + 0.1 * loss_dyn);
  }
}

// ---------------------------------------------------------------------------
// Kernel 3: out[bh, l, d] = g[bh, l, cat(l,d)] + (l==d).
// 2048 blocks x 256 threads; each block covers 64 consecutive rows (128 KB).
// g staged in LDS (192 coalesced floats); 32 iters x 2 rows of float4 stores.
// ---------------------------------------------------------------------------
__global__ __launch_bounds__(256) void out_kernel(
    const float* __restrict__ g, float* __restrict__ out) {
  __shared__ float s_g[64][3];
  const int t = threadIdx.x;
  const int r0 = blockIdx.x * 64;          // first row of this block
  if (t < 192) s_g[t / 3][t % 3] = g[r0 * 3 + t];
  __syncthreads();

  const int half = t >> 7;                 // 0/1: row parity within pair
  const int tt = t & 127;
  const int d0 = tt * 4;
  const int l0 = r0 & (kL - 1);            // l of local row 0 (r0 % 512)
  float* ob = out + (size_t)r0 * kL;
  for (int rr = 0; rr < 64; rr += 2) {
    const int row = rr + half;
    const int l = l0 + row;
    const float g0 = s_g[row][0];
    const float g1 = s_g[row][1];
    const float g2 = s_g[row][2];
    const int lblk = l >> 6;
    const int loff = l & 63;
    float vals[4];
#pragma unroll
    for (int q = 0; q < 4; ++q) {
      const int d = d0 + q;
      float v;
      if ((d >> 6) == lblk) v = g1;                    // T (includes diagonal)
      else if ((d & 63) == loff) v = g0;               // S
      else v = g2;                                     // ST
      if (d == l) v += 1.0f;                           // + eye
      vals[q] = v;
    }
    *reinterpret_cast<float4*>(ob + (size_t)row * kL + d0) =
        *reinterpret_cast<float4*>(vals);
  }
}

}  // namespace

extern "C" void kernel_launch(void* const* d_in, const int* in_sizes, int n_in,
                              void* d_out, int out_size, void* d_ws, size_t ws_size,
                              hipStream_t stream) {
  (void)in_sizes; (void)n_in; (void)out_size; (void)ws_size;
  const float* x = (const float*)d_in[0];       // [B,H,L,L] = [32,8,512,512]
  const float* gw = (const float*)d_in[1];      // [3,512]
  const float* nw = (const float*)d_in[2];      // [3,512]
  float* out = (float*)d_out;                   // 64M out + 1 loss

  float* ws = (float*)d_ws;
  float* ws_g = ws;                               // kRows*3 floats
  float* ws_kept = ws + (size_t)kRows * 3;        // kRows*3 floats
  float* ws_ent = ws + (size_t)kRows * 6;         // kRows floats
  double* ws_imp = (double*)(ws + (size_t)kRows * 7);   // 1536 doubles (8B-aligned)
  double* ws_entp = ws_imp + kL * kE;                   // 128 doubles

  gating_kernel<<<kRows / 256, 256, 0, stream>>>(x, gw, nw, ws_g, ws_kept, ws_ent);
  loss_partial_kernel<<<128, 256, 0, stream>>>(ws_kept, ws_ent, ws_imp, ws_entp);
  loss_final_kernel<<<1, 256, 0, stream>>>(ws_imp, ws_entp,
                                           out + (size_t)kBH * kL * kL);
  out_kernel<<<kRows / 64, 256, 0, stream>>>(ws_g, out);
}

// Round 8
// 186.080 us; speedup vs baseline: 1.0064x; 1.0064x over previous
//
#include <hip/hip_runtime.h>
#include <cstdint>
#include <cstddef>

// ---------------------------------------------------------------------------
// mask_moe: bit-exact vs harness reference (verified rounds 4/5/6/7, absmax 0).
// FROZEN arithmetic: partitionable threefry bits, f32 sequential-k FMA dots,
// f32 elementwise chain (softplus/normal/softmax), decision logic.
// Round 8: fuse out-write into gating (round-5 retry with both failure causes
// fixed): LDS-staged coalesced reads (r6) + sequential-per-wave write streams
// (r7 lesson: no strided per-wave store loops). s_g aliases dead s_x.
// ---------------------------------------------------------------------------

namespace {

constexpr int kBH = 256;                  // B*H
constexpr int kL = 512;                   // L
constexpr int kE = 3;                     // experts
constexpr int kRows = kBH * kL;           // 131072 gating rows
constexpr int kXPad = 65;                 // LDS row stride (floats), bank-safe

__device__ __forceinline__ uint32_t rotl32(uint32_t v, int n) {
  return (v << n) | (v >> (32 - n));
}

// Threefry-2x32, 20 rounds, key = (0, 42)  [jax.random.key(42)]
__device__ __forceinline__ void threefry2x32_k42(uint32_t& x0, uint32_t& x1) {
  const uint32_t ks0 = 0u;
  const uint32_t ks1 = 42u;
  const uint32_t ks2 = 0u ^ 42u ^ 0x1BD11BDAu;
  x0 += ks0; x1 += ks1;
#define TF_ROUND(r) { x0 += x1; x1 = rotl32(x1, (r)); x1 ^= x0; }
  TF_ROUND(13) TF_ROUND(15) TF_ROUND(26) TF_ROUND(6)
  x0 += ks1; x1 += ks2 + 1u;
  TF_ROUND(17) TF_ROUND(29) TF_ROUND(16) TF_ROUND(24)
  x0 += ks2; x1 += ks0 + 2u;
  TF_ROUND(13) TF_ROUND(15) TF_ROUND(26) TF_ROUND(6)
  x0 += ks0; x1 += ks1 + 3u;
  TF_ROUND(17) TF_ROUND(29) TF_ROUND(16) TF_ROUND(24)
  x0 += ks1; x1 += ks2 + 4u;
  TF_ROUND(13) TF_ROUND(15) TF_ROUND(26) TF_ROUND(6)
  x0 += ks2; x1 += ks0 + 5u;
#undef TF_ROUND
}

// partitionable path: bits = x0 ^ x1 of threefry(key, (0, i))
__device__ __forceinline__ uint32_t jax_random_bits(uint32_t flat_idx) {
  uint32_t x0 = 0u;
  uint32_t x1 = flat_idx;
  threefry2x32_k42(x0, x1);
  return x0 ^ x1;
}

// jax.random.normal f32: uniform(-0.99999994, 1.0) then sqrt(2)*erfinv (XLA Giles poly)
__device__ float bits_to_normal(uint32_t bits) {
#pragma clang fp contract(off)
  const uint32_t fb = (bits >> 9) | 0x3F800000u;
  const float f = __uint_as_float(fb) - 1.0f;   // [0, 1)
  const float lo = -0.99999994f;                 // nextafterf(-1, 0)
  float u = f * 2.0f + lo;                       // (maxval-minval) == 2.0f exactly
  u = fmaxf(lo, u);
  float w = -log1pf(-(u * u));
  float p;
  if (w < 5.0f) {
    w = w - 2.5f;
    p = 2.81022636e-08f;
    p = 3.43273939e-07f + p * w;
    p = -3.5233877e-06f + p * w;
    p = -4.39150654e-06f + p * w;
    p = 0.00021858087f + p * w;
    p = -0.00125372503f + p * w;
    p = -0.00417768164f + p * w;
    p = 0.246640727f + p * w;
    p = 1.50140941f + p * w;
  } else {
    w = sqrtf(w) - 3.0f;
    p = -0.000200214257f;
    p = 0.000100950558f + p * w;
    p = 0.00134934322f + p * w;
    p = -0.00367342844f + p * w;
    p = 0.00573950773f + p * w;
    p = -0.0076224613f + p * w;
    p = 0.00943887047f + p * w;
    p = 1.00167406f + p * w;
    p = 2.83297682f + p * w;
  }
  const float einv = p * u;
  return 1.41421354f * einv;  // f32(sqrt(2)) * erfinv(u)
}

// jax.nn.softplus(x) = logaddexp(x, 0) = max(x,0) + log1p(exp(-|x|))
__device__ __forceinline__ float softplus_f32(float v) {
#pragma clang fp contract(off)
  const float amax = fmaxf(v, 0.0f);
  return amax + log1pf(expf(-fabsf(v)));
}

// ---------------------------------------------------------------------------
// Fused kernel: gating + output write. 512 blocks x 256 threads.
// Phase A (r6-proven): x staged through LDS in 64-col tiles, coalesced
//   cooperative float4 loads (pad-65, conflict-free); FROZEN f32
//   sequential-k single-accumulator FMA dots per thread-row.
// Epilogue: decisions -> s_g (aliases dead s_x), kept/ent -> ws.
// Phase B: wave w writes rows [64w, 64w+64) of the block -- one fully
//   sequential 128 KB stream per wave (r7 lesson).
// ---------------------------------------------------------------------------
__global__ __launch_bounds__(256) void fused_kernel(
    const float* __restrict__ x, const float* __restrict__ gw,
    const float* __restrict__ nw, float* __restrict__ out,
    float* __restrict__ kept_out, float* __restrict__ ent_out) {
  __shared__ float s_gw[kE * kL];
  __shared__ float s_nw[kE * kL];
  __shared__ float s_x[256 * kXPad];   // 66,560 B tile; reused as s_g later
  const int t = threadIdx.x;
  for (int i = t; i < kE * kL; i += 256) {
    s_gw[i] = gw[i];
    s_nw[i] = nw[i];
  }

  const int r0 = blockIdx.x * 256;
  const int r = r0 + t;  // this thread's row

  float accg[3] = {0.f, 0.f, 0.f};
  float accn[3] = {0.f, 0.f, 0.f};
  for (int c0 = 0; c0 < kL; c0 += 64) {
    __syncthreads();   // LDS tile reuse barrier (also covers weight staging)
    // cooperative coalesced load: 4096 float4s, 16 per thread
#pragma unroll
    for (int it = 0; it < 16; ++it) {
      const int fi = it * 256 + t;       // float4 index in tile
      const int row = fi >> 4;           // /16 float4s per row
      const int c4 = (fi & 15) << 2;     // col offset
      const float4 v =
          *reinterpret_cast<const float4*>(x + (size_t)(r0 + row) * kL + c0 + c4);
      float* dst = &s_x[row * kXPad + c4];
      dst[0] = v.x; dst[1] = v.y; dst[2] = v.z; dst[3] = v.w;
    }
    __syncthreads();
    {
#pragma clang fp contract(off)
      const float* xrow = &s_x[t * kXPad];
#pragma unroll 16
      for (int kk = 0; kk < 64; ++kk) {
        const float xq = xrow[kk];
        const int k = c0 + kk;
        accg[0] = fmaf(xq, s_gw[0 * kL + k], accg[0]);
        accg[1] = fmaf(xq, s_gw[1 * kL + k], accg[1]);
        accg[2] = fmaf(xq, s_gw[2 * kL + k], accg[2]);
        accn[0] = fmaf(xq, s_nw[0 * kL + k], accn[0]);
        accn[1] = fmaf(xq, s_nw[1 * kL + k], accn[1]);
        accn[2] = fmaf(xq, s_nw[2 * kL + k], accn[2]);
      }
    }
  }
  __syncthreads();   // all compute-phase s_x reads done before s_g aliasing

  {
#pragma clang fp contract(off)
    float noisy[3];
    const uint32_t nbase = (uint32_t)r * 3u;
#pragma unroll
    for (int e = 0; e < 3; ++e) {
      const float cl = accg[e];
      const float sp = softplus_f32(accn[e]) + 0.01f;  // NOISE_EPS
      const float nz = bits_to_normal(jax_random_bits(nbase + (uint32_t)e));
      const float prod = nz * sp;        // separate rounding: mul then add
      noisy[e] = cl + prod;
    }
    // softmax over 3 experts (f32, max-subtracted)
    const float m = fmaxf(noisy[0], fmaxf(noisy[1], noisy[2]));
    float uu[3];
    uu[0] = expf(noisy[0] - m);
    uu[1] = expf(noisy[1] - m);
    uu[2] = expf(noisy[2] - m);
    const float ssum = (uu[0] + uu[1]) + uu[2];
    float p[3];
    p[0] = uu[0] / ssum;
    p[1] = uu[1] / ssum;
    p[2] = uu[2] / ssum;

    // stable descending argsort of 3
    int o0 = 0;
    if (p[1] > p[o0]) o0 = 1;
    if (p[2] > p[o0]) o0 = 2;
    const int i = (o0 == 0) ? 1 : 0;
    const int j = (o0 == 2) ? 1 : 2;
    const int o1 = (p[j] > p[i]) ? j : i;

    const float s0 = p[o0];
    const float s1 = p[o1];
    const bool keep2 = !(s0 > 0.5f);  // keep top-1 iff s0 > 0.5

    float g[3] = {0.f, 0.f, 0.f};
    g[o0] = 1.f;
    if (keep2) g[o1] = 1.f;

    float ent = 0.f;
    ent += p[0] * logf(p[0] + 1e-10f);
    ent += p[1] * logf(p[1] + 1e-10f);
    ent += p[2] * logf(p[2] + 1e-10f);

    const int bh = r >> 9;
    const int l = r & (kL - 1);
    // s_g aliases s_x (dead after compute phases)
    s_x[t * 3 + 0] = g[0];
    s_x[t * 3 + 1] = g[1];
    s_x[t * 3 + 2] = g[2];
    // kept sorted probs, layout [jpos][l][bh] for coalesced reduction reads
    kept_out[(0 * kL + l) * kBH + bh] = s0;
    kept_out[(1 * kL + l) * kBH + bh] = keep2 ? s1 : 0.f;
    kept_out[(2 * kL + l) * kBH + bh] = 0.f;
    ent_out[r] = -ent;
  }
  __syncthreads();   // s_g visible to all

  // Phase B: wave wv writes rows [64*wv, 64*wv+64) -- sequential 128 KB/wave.
  const int wv = t >> 6;
  const int ln = t & 63;
  const int row0 = wv * 64;
  const int l0 = (blockIdx.x & 1) * 256;     // l of local row 0
  float* ob = out + (size_t)(r0 + row0) * kL;
  for (int rr = 0; rr < 64; ++rr) {
    const int row = row0 + rr;
    const int l = l0 + row;
    const float g0 = s_x[row * 3 + 0];       // wave-uniform broadcast reads
    const float g1 = s_x[row * 3 + 1];
    const float g2 = s_x[row * 3 + 2];
    const int lblk = l >> 6;
    const int loff = l & 63;
#pragma unroll
    for (int hseg = 0; hseg < 2; ++hseg) {
      const int d0 = hseg * 256 + ln * 4;
      float vals[4];
#pragma unroll
      for (int q = 0; q < 4; ++q) {
        const int d = d0 + q;
        float v;
        if ((d >> 6) == lblk) v = g1;                  // T (includes diagonal)
        else if ((d & 63) == loff) v = g0;             // S
        else v = g2;                                   // ST
        if (d == l) v += 1.0f;                         // + eye
        vals[q] = v;
      }
      *reinterpret_cast<float4*>(ob + (size_t)rr * kL + d0) =
          *reinterpret_cast<float4*>(vals);
    }
  }
}

// ---------------------------------------------------------------------------
// Kernel 2a: parallel deterministic partials.
// 128 blocks x 256 threads (512 waves). Importance: wave wg reduces entries
// q = wg, wg+512, wg+1024 (coalesced 1KB float4 read + fixed f64 butterfly).
// Entropy: each block reduces a fixed 1024-row slice with a fixed LDS tree.
// ---------------------------------------------------------------------------
__global__ __launch_bounds__(256) void loss_partial_kernel(
    const float* __restrict__ kept, const float* __restrict__ ent,
    double* __restrict__ imp_ws, double* __restrict__ ent_ws) {
  __shared__ double red[256];
  const int t = threadIdx.x;
  const int ln = t & 63;
  const int wg = blockIdx.x * 4 + (t >> 6);   // global wave id, 0..511

  // importance entries
#pragma unroll
  for (int rep = 0; rep < 3; ++rep) {
    const int q = wg + rep * 512;
    const float4 v = reinterpret_cast<const float4*>(kept + (size_t)q * kBH)[ln];
    double s = ((double)v.x + (double)v.y) + ((double)v.z + (double)v.w);
#pragma unroll
    for (int off = 32; off > 0; off >>= 1) s += __shfl_xor(s, off, 64);
    if (ln == 0) imp_ws[q] = s;
  }

  // entropy partial: fixed slice of 1024 rows
  double a = 0.0;
#pragma unroll
  for (int it = 0; it < 4; ++it) {
    a += (double)ent[blockIdx.x * 1024 + it * 256 + t];
  }
  red[t] = a;
  __syncthreads();
  for (int off = 128; off > 0; off >>= 1) {
    if (t < off) red[t] += red[t + off];
    __syncthreads();
  }
  if (t == 0) ent_ws[blockIdx.x] = red[0];
}

// ---------------------------------------------------------------------------
// Kernel 2b: final loss combine (1 block, trivial).
// loss = var(importance, ddof=1)/(mean^2 + 1e-10) + 0.1 * ent_total/768
// ---------------------------------------------------------------------------
__global__ __launch_bounds__(256) void loss_final_kernel(
    const double* __restrict__ imp_ws, const double* __restrict__ ent_ws,
    float* __restrict__ loss_out) {
  __shared__ double red[256];
  __shared__ double s_mean;
  const int t = threadIdx.x;

  // mean of importance
  double a = 0.0;
  for (int i = t; i < kL * kE; i += 256) a += imp_ws[i];
  red[t] = a;
  __syncthreads();
  for (int off = 128; off > 0; off >>= 1) {
    if (t < off) red[t] += red[t + off];
    __syncthreads();
  }
  if (t == 0) s_mean = red[0] / (double)(kL * kE);
  __syncthreads();
  const double mean = s_mean;

  // variance (two-pass, ddof=1)
  double sq = 0.0;
  for (int i = t; i < kL * kE; i += 256) {
    const double d = imp_ws[i] - mean;
    sq += d * d;
  }
  red[t] = sq;
  __syncthreads();
  for (int off = 128; off > 0; off >>= 1) {
    if (t < off) red[t] += red[t + off];
    __syncthreads();
  }
  const double var_sum = red[0];
  __syncthreads();

  // entropy total
  double e = 0.0;
  for (int i = t; i < 128; i += 256) e += ent_ws[i];
  red[t] = e;
  __syncthreads();
  for (int off = 128; off > 0; off >>= 1) {
    if (t < off) red[t] += red[t + off];
    __syncthreads();
  }
  if (t == 0) {
    const double var = var_sum / (double)(kL * kE - 1);
    const double loss_imp = var / (mean * mean + 1e-10);
    const double loss_dyn = red[0] / 768.0;  // sum(axis=1).mean() over [BH,E]
    loss_out[0] = (float)(loss_imp + 0.1 * loss_dyn);
  }
}

}  // namespace

extern "C" void kernel_launch(void* const* d_in, const int* in_sizes, int n_in,
                              void* d_out, int out_size, void* d_ws, size_t ws_size,
                              hipStream_t stream) {
  (void)in_sizes; (void)n_in; (void)out_size; (void)ws_size;
  const float* x = (const float*)d_in[0];       // [B,H,L,L] = [32,8,512,512]
  const float* gw = (const float*)d_in[1];      // [3,512]
  const float* nw = (const float*)d_in[2];      // [3,512]
  float* out = (float*)d_out;                   // 64M out + 1 loss

  float* ws = (float*)d_ws;
  float* ws_kept = ws;                            // kRows*3 floats
  float* ws_ent = ws + (size_t)kRows * 3;         // kRows floats
  double* ws_imp = (double*)(ws + (size_t)kRows * 4);   // 1536 doubles (8B-aligned)
  double* ws_entp = ws_imp + kL * kE;                   // 128 doubles

  fused_kernel<<<kRows / 256, 256, 0, stream>>>(x, gw, nw, out, ws_kept, ws_ent);
  loss_partial_kernel<<<128, 256, 0, stream>>>(ws_kept, ws_ent, ws_imp, ws_entp);
  loss_final_kernel<<<1, 256, 0, stream>>>(ws_imp, ws_entp,
                                           out + (size_t)kBH * kL * kL);
}

// Round 9
// 147.384 us; speedup vs baseline: 1.2706x; 1.2625x over previous
//
#include <hip/hip_runtime.h>
#include <cstdint>
#include <cstddef>

// ---------------------------------------------------------------------------
// mask_moe: bit-exact vs harness reference (verified r4-r8, absmax 0.0).
// FROZEN arithmetic: partitionable threefry bits, f32 sequential-k FMA dots,
// f32 elementwise chain (softplus/normal/softmax), decision logic.
// Round 9: revert to r6 3-kernel structure (148.7 us proven; fusion refuted
// twice). Gating: drop s_x LDS tile (direct per-thread float4 x streaming,
// no LDS occupancy cap) + float4 weight reads (LDS instrs/wave 3584 -> 896;
// LDS pipe was the modeled bottleneck). FMA sequence operand-identical.
// ---------------------------------------------------------------------------

namespace {

constexpr int kBH = 256;                  // B*H
constexpr int kL = 512;                   // L
constexpr int kE = 3;                     // experts
constexpr int kRows = kBH * kL;           // 131072 gating rows

__device__ __forceinline__ uint32_t rotl32(uint32_t v, int n) {
  return (v << n) | (v >> (32 - n));
}

// Threefry-2x32, 20 rounds, key = (0, 42)  [jax.random.key(42)]
__device__ __forceinline__ void threefry2x32_k42(uint32_t& x0, uint32_t& x1) {
  const uint32_t ks0 = 0u;
  const uint32_t ks1 = 42u;
  const uint32_t ks2 = 0u ^ 42u ^ 0x1BD11BDAu;
  x0 += ks0; x1 += ks1;
#define TF_ROUND(r) { x0 += x1; x1 = rotl32(x1, (r)); x1 ^= x0; }
  TF_ROUND(13) TF_ROUND(15) TF_ROUND(26) TF_ROUND(6)
  x0 += ks1; x1 += ks2 + 1u;
  TF_ROUND(17) TF_ROUND(29) TF_ROUND(16) TF_ROUND(24)
  x0 += ks2; x1 += ks0 + 2u;
  TF_ROUND(13) TF_ROUND(15) TF_ROUND(26) TF_ROUND(6)
  x0 += ks0; x1 += ks1 + 3u;
  TF_ROUND(17) TF_ROUND(29) TF_ROUND(16) TF_ROUND(24)
  x0 += ks1; x1 += ks2 + 4u;
  TF_ROUND(13) TF_ROUND(15) TF_ROUND(26) TF_ROUND(6)
  x0 += ks2; x1 += ks0 + 5u;
#undef TF_ROUND
}

// partitionable path: bits = x0 ^ x1 of threefry(key, (0, i))
__device__ __forceinline__ uint32_t jax_random_bits(uint32_t flat_idx) {
  uint32_t x0 = 0u;
  uint32_t x1 = flat_idx;
  threefry2x32_k42(x0, x1);
  return x0 ^ x1;
}

// jax.random.normal f32: uniform(-0.99999994, 1.0) then sqrt(2)*erfinv (XLA Giles poly)
__device__ float bits_to_normal(uint32_t bits) {
#pragma clang fp contract(off)
  const uint32_t fb = (bits >> 9) | 0x3F800000u;
  const float f = __uint_as_float(fb) - 1.0f;   // [0, 1)
  const float lo = -0.99999994f;                 // nextafterf(-1, 0)
  float u = f * 2.0f + lo;                       // (maxval-minval) == 2.0f exactly
  u = fmaxf(lo, u);
  float w = -log1pf(-(u * u));
  float p;
  if (w < 5.0f) {
    w = w - 2.5f;
    p = 2.81022636e-08f;
    p = 3.43273939e-07f + p * w;
    p = -3.5233877e-06f + p * w;
    p = -4.39150654e-06f + p * w;
    p = 0.00021858087f + p * w;
    p = -0.00125372503f + p * w;
    p = -0.00417768164f + p * w;
    p = 0.246640727f + p * w;
    p = 1.50140941f + p * w;
  } else {
    w = sqrtf(w) - 3.0f;
    p = -0.000200214257f;
    p = 0.000100950558f + p * w;
    p = 0.00134934322f + p * w;
    p = -0.00367342844f + p * w;
    p = 0.00573950773f + p * w;
    p = -0.0076224613f + p * w;
    p = 0.00943887047f + p * w;
    p = 1.00167406f + p * w;
    p = 2.83297682f + p * w;
  }
  const float einv = p * u;
  return 1.41421354f * einv;  // f32(sqrt(2)) * erfinv(u)
}

// jax.nn.softplus(x) = logaddexp(x, 0) = max(x,0) + log1p(exp(-|x|))
__device__ __forceinline__ float softplus_f32(float v) {
#pragma clang fp contract(off)
  const float amax = fmaxf(v, 0.0f);
  return amax + log1pf(expf(-fabsf(v)));
}

// ---------------------------------------------------------------------------
// Kernel 1: gating. One thread per row; x streamed directly per thread as
// sequential float4s (64B-line reuse across 4 consecutive loads); weights in
// LDS read as float4 broadcasts (6 ds_read_b128 per 4 k-steps).
// FROZEN: f32 sequential-k single-accumulator FMA order per expert.
// ---------------------------------------------------------------------------
__global__ __launch_bounds__(256) void gating_kernel(
    const float* __restrict__ x, const float* __restrict__ gw,
    const float* __restrict__ nw, float* __restrict__ g_out,
    float* __restrict__ kept_out, float* __restrict__ ent_out) {
  __shared__ float s_gw[kE * kL];
  __shared__ float s_nw[kE * kL];
  const int t = threadIdx.x;
  for (int i = t; i < kE * kL; i += 256) {
    s_gw[i] = gw[i];
    s_nw[i] = nw[i];
  }
  __syncthreads();

  const int r = blockIdx.x * 256 + t;  // row id in [0, kRows)
  const float* xr = x + (size_t)r * kL;

  float accg[3] = {0.f, 0.f, 0.f};
  float accn[3] = {0.f, 0.f, 0.f};
  {
#pragma clang fp contract(off)
    for (int k0 = 0; k0 < kL; k0 += 16) {
      float4 xv[4];
      xv[0] = *reinterpret_cast<const float4*>(xr + k0);
      xv[1] = *reinterpret_cast<const float4*>(xr + k0 + 4);
      xv[2] = *reinterpret_cast<const float4*>(xr + k0 + 8);
      xv[3] = *reinterpret_cast<const float4*>(xr + k0 + 12);
#pragma unroll
      for (int j = 0; j < 4; ++j) {
        const int k = k0 + j * 4;
        const float4 wg0 = *reinterpret_cast<const float4*>(&s_gw[0 * kL + k]);
        const float4 wg1 = *reinterpret_cast<const float4*>(&s_gw[1 * kL + k]);
        const float4 wg2 = *reinterpret_cast<const float4*>(&s_gw[2 * kL + k]);
        const float4 wn0 = *reinterpret_cast<const float4*>(&s_nw[0 * kL + k]);
        const float4 wn1 = *reinterpret_cast<const float4*>(&s_nw[1 * kL + k]);
        const float4 wn2 = *reinterpret_cast<const float4*>(&s_nw[2 * kL + k]);
        const float4 xq = xv[j];
        // ascending k, accumulator order g0,g1,g2,n0,n1,n2 — FROZEN sequence
        accg[0] = fmaf(xq.x, wg0.x, accg[0]);
        accg[1] = fmaf(xq.x, wg1.x, accg[1]);
        accg[2] = fmaf(xq.x, wg2.x, accg[2]);
        accn[0] = fmaf(xq.x, wn0.x, accn[0]);
        accn[1] = fmaf(xq.x, wn1.x, accn[1]);
        accn[2] = fmaf(xq.x, wn2.x, accn[2]);

        accg[0] = fmaf(xq.y, wg0.y, accg[0]);
        accg[1] = fmaf(xq.y, wg1.y, accg[1]);
        accg[2] = fmaf(xq.y, wg2.y, accg[2]);
        accn[0] = fmaf(xq.y, wn0.y, accn[0]);
        accn[1] = fmaf(xq.y, wn1.y, accn[1]);
        accn[2] = fmaf(xq.y, wn2.y, accn[2]);

        accg[0] = fmaf(xq.z, wg0.z, accg[0]);
        accg[1] = fmaf(xq.z, wg1.z, accg[1]);
        accg[2] = fmaf(xq.z, wg2.z, accg[2]);
        accn[0] = fmaf(xq.z, wn0.z, accn[0]);
        accn[1] = fmaf(xq.z, wn1.z, accn[1]);
        accn[2] = fmaf(xq.z, wn2.z, accn[2]);

        accg[0] = fmaf(xq.w, wg0.w, accg[0]);
        accg[1] = fmaf(xq.w, wg1.w, accg[1]);
        accg[2] = fmaf(xq.w, wg2.w, accg[2]);
        accn[0] = fmaf(xq.w, wn0.w, accn[0]);
        accn[1] = fmaf(xq.w, wn1.w, accn[1]);
        accn[2] = fmaf(xq.w, wn2.w, accn[2]);
      }
    }
  }

  {
#pragma clang fp contract(off)
    float noisy[3];
    const uint32_t nbase = (uint32_t)r * 3u;
#pragma unroll
    for (int e = 0; e < 3; ++e) {
      const float cl = accg[e];
      const float sp = softplus_f32(accn[e]) + 0.01f;  // NOISE_EPS
      const float nz = bits_to_normal(jax_random_bits(nbase + (uint32_t)e));
      const float prod = nz * sp;        // separate rounding: mul then add
      noisy[e] = cl + prod;
    }
    // softmax over 3 experts (f32, max-subtracted)
    const float m = fmaxf(noisy[0], fmaxf(noisy[1], noisy[2]));
    float uu[3];
    uu[0] = expf(noisy[0] - m);
    uu[1] = expf(noisy[1] - m);
    uu[2] = expf(noisy[2] - m);
    const float ssum = (uu[0] + uu[1]) + uu[2];
    float p[3];
    p[0] = uu[0] / ssum;
    p[1] = uu[1] / ssum;
    p[2] = uu[2] / ssum;

    // stable descending argsort of 3
    int o0 = 0;
    if (p[1] > p[o0]) o0 = 1;
    if (p[2] > p[o0]) o0 = 2;
    const int i = (o0 == 0) ? 1 : 0;
    const int j = (o0 == 2) ? 1 : 2;
    const int o1 = (p[j] > p[i]) ? j : i;

    const float s0 = p[o0];
    const float s1 = p[o1];
    const bool keep2 = !(s0 > 0.5f);  // keep top-1 iff s0 > 0.5

    float g[3] = {0.f, 0.f, 0.f};
    g[o0] = 1.f;
    if (keep2) g[o1] = 1.f;

    float ent = 0.f;
    ent += p[0] * logf(p[0] + 1e-10f);
    ent += p[1] * logf(p[1] + 1e-10f);
    ent += p[2] * logf(p[2] + 1e-10f);

    const int bh = r >> 9;
    const int l = r & (kL - 1);
    g_out[r * 3 + 0] = g[0];
    g_out[r * 3 + 1] = g[1];
    g_out[r * 3 + 2] = g[2];
    // kept sorted probs, layout [jpos][l][bh] for coalesced reduction reads
    kept_out[(0 * kL + l) * kBH + bh] = s0;
    kept_out[(1 * kL + l) * kBH + bh] = keep2 ? s1 : 0.f;
    kept_out[(2 * kL + l) * kBH + bh] = 0.f;
    ent_out[r] = -ent;
  }
}

// ---------------------------------------------------------------------------
// Kernel 2a: parallel deterministic partials.
// 128 blocks x 256 threads (512 waves). Importance: wave wg reduces entries
// q = wg, wg+512, wg+1024 (coalesced 1KB float4 read + fixed f64 butterfly).
// Entropy: each block reduces a fixed 1024-row slice with a fixed LDS tree.
// ---------------------------------------------------------------------------
__global__ __launch_bounds__(256) void loss_partial_kernel(
    const float* __restrict__ kept, const float* __restrict__ ent,
    double* __restrict__ imp_ws, double* __restrict__ ent_ws) {
  __shared__ double red[256];
  const int t = threadIdx.x;
  const int ln = t & 63;
  const int wg = blockIdx.x * 4 + (t >> 6);   // global wave id, 0..511

  // importance entries
#pragma unroll
  for (int rep = 0; rep < 3; ++rep) {
    const int q = wg + rep * 512;
    const float4 v = reinterpret_cast<const float4*>(kept + (size_t)q * kBH)[ln];
    double s = ((double)v.x + (double)v.y) + ((double)v.z + (double)v.w);
#pragma unroll
    for (int off = 32; off > 0; off >>= 1) s += __shfl_xor(s, off, 64);
    if (ln == 0) imp_ws[q] = s;
  }

  // entropy partial: fixed slice of 1024 rows
  double a = 0.0;
#pragma unroll
  for (int it = 0; it < 4; ++it) {
    a += (double)ent[blockIdx.x * 1024 + it * 256 + t];
  }
  red[t] = a;
  __syncthreads();
  for (int off = 128; off > 0; off >>= 1) {
    if (t < off) red[t] += red[t + off];
    __syncthreads();
  }
  if (t == 0) ent_ws[blockIdx.x] = red[0];
}

// ---------------------------------------------------------------------------
// Kernel 2b: final loss combine (1 block, trivial).
// loss = var(importance, ddof=1)/(mean^2 + 1e-10) + 0.1 * ent_total/768
// ---------------------------------------------------------------------------
__global__ __launch_bounds__(256) void loss_final_kernel(
    const double* __restrict__ imp_ws, const double* __restrict__ ent_ws,
    float* __restrict__ loss_out) {
  __shared__ double red[256];
  __shared__ double s_mean;
  const int t = threadIdx.x;

  // mean of importance
  double a = 0.0;
  for (int i = t; i < kL * kE; i += 256) a += imp_ws[i];
  red[t] = a;
  __syncthreads();
  for (int off = 128; off > 0; off >>= 1) {
    if (t < off) red[t] += red[t + off];
    __syncthreads();
  }
  if (t == 0) s_mean = red[0] / (double)(kL * kE);
  __syncthreads();
  const double mean = s_mean;

  // variance (two-pass, ddof=1)
  double sq = 0.0;
  for (int i = t; i < kL * kE; i += 256) {
    const double d = imp_ws[i] - mean;
    sq += d * d;
  }
  red[t] = sq;
  __syncthreads();
  for (int off = 128; off > 0; off >>= 1) {
    if (t < off) red[t] += red[t + off];
    __syncthreads();
  }
  const double var_sum = red[0];
  __syncthreads();

  // entropy total
  double e = 0.0;
  for (int i = t; i < 128; i += 256) e += ent_ws[i];
  red[t] = e;
  __syncthreads();
  for (int off = 128; off > 0; off >>= 1) {
    if (t < off) red[t] += red[t + off];
    __syncthreads();
  }
  if (t == 0) {
    const double var = var_sum / (double)(kL * kE - 1);
    const double loss_imp = var / (mean * mean + 1e-10);
    const double loss_dyn = red[0] / 768.0;  // sum(axis=1).mean() over [BH,E]
    loss_out[0] = (float)(loss_imp + 0.1 * loss_dyn);
  }
}

// ---------------------------------------------------------------------------
// Kernel 3: out[bh, l, d] = g[bh, l, cat(l,d)] + (l==d). One block per row,
// 128 threads x float4 = 512 coalesced writes. (r6-proven form — fastest.)
// ---------------------------------------------------------------------------
__global__ __launch_bounds__(128) void out_kernel(
    const float* __restrict__ g, float* __restrict__ out) {
  const int r = blockIdx.x;
  const int l = r & (kL - 1);
  const float g0 = g[r * 3 + 0];
  const float g1 = g[r * 3 + 1];
  const float g2 = g[r * 3 + 2];
  const int lblk = l >> 6;
  const int loff = l & 63;
  const int d0 = threadIdx.x * 4;
  float vals[4];
#pragma unroll
  for (int k = 0; k < 4; ++k) {
    const int d = d0 + k;
    float v;
    if (((d & 63) == loff) && (d != l)) v = g0;       // S
    else if ((d >> 6) == lblk) v = g1;                 // T (includes diagonal)
    else v = g2;                                       // ST
    if (d == l) v += 1.0f;                             // + eye
    vals[k] = v;
  }
  *reinterpret_cast<float4*>(out + (size_t)r * kL + d0) =
      *reinterpret_cast<float4*>(vals);
}

}  // namespace

extern "C" void kernel_launch(void* const* d_in, const int* in_sizes, int n_in,
                              void* d_out, int out_size, void* d_ws, size_t ws_size,
                              hipStream_t stream) {
  (void)in_sizes; (void)n_in; (void)out_size; (void)ws_size;
  const float* x = (const float*)d_in[0];       // [B,H,L,L] = [32,8,512,512]
  const float* gw = (const float*)d_in[1];      // [3,512]
  const float* nw = (const float*)d_in[2];      // [3,512]
  float* out = (float*)d_out;                   // 64M out + 1 loss

  float* ws = (float*)d_ws;
  float* ws_g = ws;                               // kRows*3 floats
  float* ws_kept = ws + (size_t)kRows * 3;        // kRows*3 floats
  float* ws_ent = ws + (size_t)kRows * 6;         // kRows floats
  double* ws_imp = (double*)(ws + (size_t)kRows * 7);   // 1536 doubles (8B-aligned)
  double* ws_entp = ws_imp + kL * kE;                   // 128 doubles

  gating_kernel<<<kRows / 256, 256, 0, stream>>>(x, gw, nw, ws_g, ws_kept, ws_ent);
  loss_partial_kernel<<<128, 256, 0, stream>>>(ws_kept, ws_ent, ws_imp, ws_entp);
  loss_final_kernel<<<1, 256, 0, stream>>>(ws_imp, ws_entp,
                                           out + (size_t)kBH * kL * kL);
  out_kernel<<<kRows, 128, 0, stream>>>(ws_g, out);
}